// Round 9
// baseline (301.209 us; speedup 1.0000x reference)
//
#include <hip/hip_runtime.h>
#include <hip/hip_bf16.h>

#define B_ 16
#define N_ 4096
#define S_ 1024
#define K_ 32
#define D_ 64
#define M_ (B_*S_*K_)            // 524288 rows
#define EPS_ 1e-5f

#define OUT_NRM  (B_*S_*3)       // 49152
#define OUT_FEAT (2*B_*S_*3)     // 98304
#define OUT_FPS  (OUT_FEAT + B_*S_*128)  // 2195456

typedef __attribute__((ext_vector_type(8))) short bf16x8;
typedef __attribute__((ext_vector_type(4))) float f32x4;
typedef unsigned long long u64;

__device__ __forceinline__ unsigned short rnb(float x){
  return (unsigned short)((__float_as_uint(x) + 0x8000u) >> 16);
}
__device__ __forceinline__ void split1(float x, short& h, short& l){
  unsigned ux = __float_as_uint(x);
  unsigned uh = (ux + 0x8000u) & 0xFFFF0000u;
  h = (short)(uh >> 16);
  float lo = x - __uint_as_float(uh);
  l = (short)((__float_as_uint(lo) + 0x8000u) >> 16);
}
__device__ __forceinline__ unsigned f2key(float d){
  unsigned u = __float_as_uint(d);
  return u ^ ((unsigned)(((int)u) >> 31) | 0x80000000u);
}
__device__ __forceinline__ unsigned mprefix(u64 m){
  return __builtin_amdgcn_mbcnt_hi((unsigned)(m >> 32),
         __builtin_amdgcn_mbcnt_lo((unsigned)m, 0u));
}

// reduce 4 values across 16 lr-lanes
__device__ __forceinline__ float hred4_sum(const float v[4], int l){
  bool hi8 = (l & 8) != 0;
  float send0 = hi8 ? v[0] : v[2];
  float send1 = hi8 ? v[1] : v[3];
  float r0 = __shfl_xor(send0, 8);
  float r1 = __shfl_xor(send1, 8);
  float a0 = (hi8 ? v[2] : v[0]) + r0;
  float a1 = (hi8 ? v[3] : v[1]) + r1;
  bool hi4 = (l & 4) != 0;
  float send = hi4 ? a0 : a1;
  float r = __shfl_xor(send, 4);
  float a = (hi4 ? a1 : a0) + r;
  a += __shfl_xor(a, 2);
  a += __shfl_xor(a, 1);
  return a;
}
__device__ __forceinline__ float hred4_max(const float v[4], int l){
  bool hi8 = (l & 8) != 0;
  float send0 = hi8 ? v[0] : v[2];
  float send1 = hi8 ? v[1] : v[3];
  float r0 = __shfl_xor(send0, 8);
  float r1 = __shfl_xor(send1, 8);
  float a0 = fmaxf(hi8 ? v[2] : v[0], r0);
  float a1 = fmaxf(hi8 ? v[3] : v[1], r1);
  bool hi4 = (l & 4) != 0;
  float send = hi4 ? a0 : a1;
  float r = __shfl_xor(send, 4);
  float a = fmaxf(hi4 ? a1 : a0, r);
  a = fmaxf(a, __shfl_xor(a, 2));
  a = fmaxf(a, __shfl_xor(a, 1));
  return a;
}

__global__ void zero_stats_kernel(float* __restrict__ stats){
  int t = blockIdx.x*256 + threadIdx.x;
  stats[t] = 0.f;
}

__global__ void meta_kernel(const float* __restrict__ xyz, const float* __restrict__ nrm,
                            const int* __restrict__ fps, float* __restrict__ out){
  int t = blockIdx.x*256 + threadIdx.x;
  if (t >= B_*S_) return;
  int b = t >> 10;
  int n = fps[t];
  const float* xp = xyz + ((size_t)b*N_ + n)*3;
  out[t*3+0] = xp[0]; out[t*3+1] = xp[1]; out[t*3+2] = xp[2];
  const float* pp = nrm + ((size_t)b*N_ + n)*3;
  out[OUT_NRM + t*3+0] = pp[0]; out[OUT_NRM + t*3+1] = pp[1]; out[OUT_NRM + t*3+2] = pp[2];
  out[OUT_FPS + t] = (float)n;
}

__global__ void packw_kernel(const float* __restrict__ w0, const float* __restrict__ w1,
                             const float* __restrict__ w2, unsigned short* __restrict__ dst){
  int e = blockIdx.x*256 + threadIdx.x;
  if (e >= 16384) return;
  const float* W; int base;
  if (e < 4096){ W = w0; base = 0; }
  else if (e < 8192){ W = w1; base = 4096; }
  else { W = w2; base = 8192; }
  int r = e - base;
  int frag = r >> 9;
  int lane = (r >> 3) & 63;
  int j = r & 7;
  int cht = frag >> 1, ks = frag & 1;
  int m = lane & 15, quad = lane >> 4;
  int ch = cht*16 + m, k = ks*32 + quad*8 + j;
  dst[e] = rnb(W[ch*64 + k]);
}

// ---- KNN: LDS-staged xyz; 2 queries/wave; NO register arrays (two-pass) ----
__global__ __launch_bounds__(256, 2) void knn_kernel(const float* __restrict__ xyz,
                                                     const int* __restrict__ fps,
                                                     int* __restrict__ idxout){
  __shared__ float Lx[N_*3];                 // 48 KB
  __shared__ unsigned skey[4][2][96];        // 3 KB
  __shared__ unsigned short sidx[4][2][96];  // 1.5 KB
  __shared__ unsigned scnt[4][2];
  const int t = threadIdx.x, w = t >> 6, l = t & 63;
  const int b = blockIdx.x >> 7;             // 128 blocks per batch
  {
    const float4* src = (const float4*)(xyz + (size_t)b*(N_*3));
    float4* dst = (float4*)Lx;
    #pragma unroll
    for (int j = 0; j < 12; j++) dst[j*256 + t] = src[j*256 + t];
  }
  __syncthreads();
  const int q0 = blockIdx.x*8 + w*2;
  const int nq0 = fps[q0], nq1 = fps[q0+1];
  const float qx0 = Lx[nq0*3], qy0 = Lx[nq0*3+1], qz0 = Lx[nq0*3+2];
  const float qx1 = Lx[nq1*3], qy1 = Lx[nq1*3+1], qz1 = Lx[nq1*3+2];
  const float qq0 = __fadd_rn(__fadd_rn(__fmul_rn(qx0,qx0), __fmul_rn(qy0,qy0)), __fmul_rn(qz0,qz0));
  const float qq1 = __fadd_rn(__fadd_rn(__fmul_rn(qx1,qx1), __fmul_rn(qy1,qy1)), __fmul_rn(qz1,qz1));

  // pass 1: running minima only (no arrays -> deep ds_read pipelining)
  float vmin0 = 3.0e38f, vmin1 = 3.0e38f;
  #pragma unroll 8
  for (int i = 0; i < 64; i++){
    const float* p = &Lx[(i*64 + l)*3];
    float px = p[0], py = p[1], pz = p[2];
    float pp = __fadd_rn(__fadd_rn(__fmul_rn(px,px), __fmul_rn(py,py)), __fmul_rn(pz,pz));
    float dt0 = __fadd_rn(__fadd_rn(__fmul_rn(qx0,px), __fmul_rn(qy0,py)), __fmul_rn(qz0,pz));
    float d0  = __fsub_rn(__fadd_rn(qq0,pp), __fmul_rn(2.f,dt0));
    vmin0 = fminf(vmin0, d0);
    float dt1 = __fadd_rn(__fadd_rn(__fmul_rn(qx1,px), __fmul_rn(qy1,py)), __fmul_rn(qz1,pz));
    float d1  = __fsub_rn(__fadd_rn(qq1,pp), __fmul_rn(2.f,dt1));
    vmin1 = fminf(vmin1, d1);
  }
  // upper bound on rank-31 lane-min via 20-step fused ballot search (invariant: count(<=hi)>=32)
  unsigned k0 = f2key(vmin0), k1 = f2key(vmin1);
  unsigned hiA = 0xFFFFFFFFu, loA = 0, hiB = 0xFFFFFFFFu, loB = 0;
  for (int it = 0; it < 20; ++it){
    unsigned midA = loA + ((hiA - loA) >> 1);
    unsigned midB = loB + ((hiB - loB) >> 1);
    u64 mA = __ballot(k0 <= midA);
    u64 mB = __ballot(k1 <= midB);
    if (__popcll(mA) > 31) hiA = midA; else loA = midA + 1;
    if (__popcll(mB) > 31) hiB = midB; else loB = midB + 1;
  }
  const unsigned T0 = hiA, T1 = hiB;   // key-space thresholds (>=32 survivors each)

  // init survivor buffers
  skey[w][0][l] = 0xFFFFFFFFu; skey[w][1][l] = 0xFFFFFFFFu;
  sidx[w][0][l] = 0xFFFF;      sidx[w][1][l] = 0xFFFF;
  if (l < 32){
    skey[w][0][64+l] = 0xFFFFFFFFu; skey[w][1][64+l] = 0xFFFFFFFFu;
    sidx[w][0][64+l] = 0xFFFF;      sidx[w][1][64+l] = 0xFFFF;
  }
  if (l == 0){ scnt[w][0] = 0; scnt[w][1] = 0; }

  // pass 2: recompute (bit-identical), compact survivors (order-free)
  #pragma unroll 4
  for (int i = 0; i < 64; i++){
    int n = i*64 + l;
    const float* p = &Lx[n*3];
    float px = p[0], py = p[1], pz = p[2];
    float pp = __fadd_rn(__fadd_rn(__fmul_rn(px,px), __fmul_rn(py,py)), __fmul_rn(pz,pz));
    float dt0 = __fadd_rn(__fadd_rn(__fmul_rn(qx0,px), __fmul_rn(qy0,py)), __fmul_rn(qz0,pz));
    float d0  = __fsub_rn(__fadd_rn(qq0,pp), __fmul_rn(2.f,dt0));
    unsigned u0 = f2key(d0);
    if (u0 <= T0){
      unsigned pos = atomicAdd(&scnt[w][0], 1u);
      if (pos < 96){ skey[w][0][pos] = u0; sidx[w][0][pos] = (unsigned short)n; }
    }
    float dt1 = __fadd_rn(__fadd_rn(__fmul_rn(qx1,px), __fmul_rn(qy1,py)), __fmul_rn(qz1,pz));
    float d1  = __fsub_rn(__fadd_rn(qq1,pp), __fmul_rn(2.f,dt1));
    unsigned u1 = f2key(d1);
    if (u1 <= T1){
      unsigned pos = atomicAdd(&scnt[w][1], 1u);
      if (pos < 96){ skey[w][1][pos] = u1; sidx[w][1][pos] = (unsigned short)n; }
    }
  }
  const unsigned tot0 = scnt[w][0], tot1 = scnt[w][1];   // >= 32 guaranteed

  // main path: exact 32-smallest (key,idx) among <=96 survivors, fused 2 queries.
  // 44-bit pair = (key<<12)|idx; empty slots = 2^44-1 (> any real pair).
  const u64 PMAX = (1ull << 44) - 1;
  u64 pa0 = ((u64)skey[w][0][l] << 12) | (unsigned)(sidx[w][0][l] & 0xFFF);
  u64 pa1 = ((u64)skey[w][1][l] << 12) | (unsigned)(sidx[w][1][l] & 0xFFF);
  u64 pb0 = (l < 32) ? (((u64)skey[w][0][64+l] << 12) | (unsigned)(sidx[w][0][64+l] & 0xFFF)) : PMAX;
  u64 pb1 = (l < 32) ? (((u64)skey[w][1][64+l] << 12) | (unsigned)(sidx[w][1][64+l] & 0xFFF)) : PMAX;
  u64 plo0 = 0, phi0 = PMAX, plo1 = 0, phi1 = PMAX;
  for (int it = 0; it < 44; ++it){
    u64 mid0 = plo0 + ((phi0 - plo0) >> 1);
    u64 mid1 = plo1 + ((phi1 - plo1) >> 1);
    int c0 = __popcll(__ballot(pa0 <= mid0)) + __popcll(__ballot(pb0 <= mid0));
    int c1 = __popcll(__ballot(pa1 <= mid1)) + __popcll(__ballot(pb1 <= mid1));
    if (c0 >= 32) phi0 = mid0; else plo0 = mid0 + 1;
    if (c1 >= 32) phi1 = mid1; else plo1 = mid1 + 1;
  }
  {  // writeout q0 (order within K irrelevant: max-pooled downstream)
    const size_t ob = (size_t)q0 * K_;
    bool sa = (pa0 <= plo0), sb = (pb0 <= plo0);
    u64 ma = __ballot(sa), mb = __ballot(sb);
    if (sa) idxout[ob + mprefix(ma)] = (int)(pa0 & 0xFFFull);
    if (sb) idxout[ob + __popcll(ma) + mprefix(mb)] = (int)(pb0 & 0xFFFull);
  }
  {  // writeout q1
    const size_t ob = (size_t)(q0+1) * K_;
    bool sa = (pa1 <= plo1), sb = (pb1 <= plo1);
    u64 ma = __ballot(sa), mb = __ballot(sb);
    if (sa) idxout[ob + mprefix(ma)] = (int)(pa1 & 0xFFFull);
    if (sb) idxout[ob + __popcll(ma) + mprefix(mb)] = (int)(pb1 & 0xFFFull);
  }
  // ultra-rare exact fallback (overflow beyond 96): recompute-bisection, overwrite
  #pragma unroll 1
  for (int qi = 0; qi < 2; qi++){
    unsigned tot = qi ? tot1 : tot0;
    if (tot <= 96) continue;
    float qx = qi ? qx1 : qx0, qy = qi ? qy1 : qy0, qz = qi ? qz1 : qz0, qq = qi ? qq1 : qq0;
    u64 lo = 0, hi = PMAX;
    for (int it = 0; it < 44; ++it){
      u64 mid = lo + ((hi - lo) >> 1);
      int cc = 0;
      for (int i = 0; i < 64; i++){
        int n = i*64 + l;
        const float* p = &Lx[n*3];
        float px = p[0], py = p[1], pz = p[2];
        float pp = __fadd_rn(__fadd_rn(__fmul_rn(px,px), __fmul_rn(py,py)), __fmul_rn(pz,pz));
        float dt = __fadd_rn(__fadd_rn(__fmul_rn(qx,px), __fmul_rn(qy,py)), __fmul_rn(qz,pz));
        float d  = __fsub_rn(__fadd_rn(qq,pp), __fmul_rn(2.f,dt));
        u64 pr = ((u64)f2key(d) << 12) | (unsigned)n;
        cc += (pr <= mid) ? 1 : 0;
      }
      #pragma unroll
      for (int o2 = 32; o2 > 0; o2 >>= 1) cc += __shfl_xor(cc, o2);
      if (cc >= 32) hi = mid; else lo = mid + 1;
    }
    if (l == 0) scnt[w][qi] = 0;
    const size_t ob = (size_t)(q0 + qi) * K_;
    for (int i = 0; i < 64; i++){
      int n = i*64 + l;
      const float* p = &Lx[n*3];
      float px = p[0], py = p[1], pz = p[2];
      float pp = __fadd_rn(__fadd_rn(__fmul_rn(px,px), __fmul_rn(py,py)), __fmul_rn(pz,pz));
      float dt = __fadd_rn(__fadd_rn(__fmul_rn(qx,px), __fmul_rn(qy,py)), __fmul_rn(qz,pz));
      float d  = __fsub_rn(__fadd_rn(qq,pp), __fmul_rn(2.f,dt));
      u64 pr = ((u64)f2key(d) << 12) | (unsigned)n;
      if (pr <= lo){
        unsigned pos = atomicAdd(&scnt[w][qi], 1u);
        idxout[ob + pos] = n;    // exactly 32 selected; order irrelevant
      }
    }
  }
}

// ---- conv1: gather -> split-MFMA -> Y1 + stats. 64 rows/wave, grid 2048 ----
__global__ __launch_bounds__(256, 2) void conv1_mfma(const float* __restrict__ pts,
    const int* __restrict__ idx, const unsigned short* __restrict__ wpk,
    const float* __restrict__ bias, unsigned short* __restrict__ Yo,
    float* __restrict__ stats){
  __shared__ float sred[4][128];
  const int t = threadIdx.x, w = t>>6, l = t&63, quad = l>>4, lr = l&15;
  const int m0 = blockIdx.x*256;
  const int Rw = m0 + w*64;
  const int b = m0 >> 15;
  bf16x8 wf[4][2];
  #pragma unroll
  for (int c = 0; c < 4; c++)
    #pragma unroll
    for (int s = 0; s < 2; s++)
      wf[c][s] = *(const bf16x8*)(wpk + (((c*2+s)<<6) + l)*8);
  f32x4 acc[4][4];
  #pragma unroll
  for (int c = 0; c < 4; c++)
    #pragma unroll
    for (int rt = 0; rt < 4; rt++)
      acc[c][rt] = (f32x4){0.f,0.f,0.f,0.f};
  int ri[4];
  #pragma unroll
  for (int rt = 0; rt < 4; rt++) ri[rt] = idx[Rw + rt*16 + lr];
  #pragma unroll
  for (int s = 0; s < 2; s++){
    #pragma unroll
    for (int rt = 0; rt < 4; rt++){
      const float* pr = pts + ((size_t)(b*4096 + ri[rt]))*64;
      float4 v0 = *(const float4*)(pr + s*32 + quad*8);
      float4 v1 = *(const float4*)(pr + s*32 + quad*8 + 4);
      float xs[8] = {v0.x,v0.y,v0.z,v0.w,v1.x,v1.y,v1.z,v1.w};
      bf16x8 xh, xl;
      #pragma unroll
      for (int j = 0; j < 8; j++){ short hh, ll; split1(xs[j], hh, ll); xh[j]=hh; xl[j]=ll; }
      #pragma unroll
      for (int c = 0; c < 4; c++){
        acc[c][rt] = __builtin_amdgcn_mfma_f32_16x16x32_bf16(wf[c][s], xh, acc[c][rt], 0,0,0);
        acc[c][rt] = __builtin_amdgcn_mfma_f32_16x16x32_bf16(wf[c][s], xl, acc[c][rt], 0,0,0);
      }
    }
  }
  const int rtg0 = Rw >> 4;
  #pragma unroll
  for (int c = 0; c < 4; c++){
    float4 bq = *(const float4*)(bias + c*16 + quad*4);
    float bqa[4] = {bq.x, bq.y, bq.z, bq.w};
    float sv[4] = {0,0,0,0}, qv[4] = {0,0,0,0};
    int kb = c*2 + (quad>>1);
    int sub = (quad&1)*4;
    #pragma unroll
    for (int rt = 0; rt < 4; rt++){
      float y[4];
      #pragma unroll
      for (int r = 0; r < 4; r++){
        y[r] = acc[c][rt][r] + bqa[r];
        sv[r] += y[r];
        qv[r] += y[r]*y[r];
      }
      uint2 p;
      p.x = (unsigned)rnb(y[0]) | ((unsigned)rnb(y[1])<<16);
      p.y = (unsigned)rnb(y[2]) | ((unsigned)rnb(y[3])<<16);
      *(uint2*)(Yo + ((((rtg0+rt)*8 + kb)*16 + lr)*8 + sub)) = p;
    }
    float S = hred4_sum(sv, l);
    float Q = hred4_sum(qv, l);
    if ((l & 3) == 0){
      int ch = c*16 + quad*4 + ((l>>3)&1)*2 + ((l>>2)&1);
      sred[w][ch] = S;
      sred[w][64 + ch] = Q;
    }
  }
  __syncthreads();
  if (t < 128){
    float tot = sred[0][t]+sred[1][t]+sred[2][t]+sred[3][t];
    unsafeAtomicAdd(&stats[(blockIdx.x & 7)*512 + t], tot);
  }
}

// ---- conv2: Y1 -> affine+relu -> MFMA (no split) -> Y2 + stats. 64 rows/wave ----
__global__ __launch_bounds__(256, 2) void conv2_mfma(const unsigned short* __restrict__ Yi,
    const unsigned short* __restrict__ wpk, const float* __restrict__ bias,
    const float* __restrict__ aff, unsigned short* __restrict__ Yo,
    float* __restrict__ stats){
  __shared__ float sred[4][128];
  const int t = threadIdx.x, w = t>>6, l = t&63, quad = l>>4, lr = l&15;
  const int m0 = blockIdx.x*256;
  const int Rw = m0 + w*64;
  bf16x8 wf[4][2];
  #pragma unroll
  for (int c = 0; c < 4; c++)
    #pragma unroll
    for (int s = 0; s < 2; s++)
      wf[c][s] = *(const bf16x8*)(wpk + (((c*2+s)<<6) + l)*8);
  f32x4 acc[4][4];
  #pragma unroll
  for (int c = 0; c < 4; c++)
    #pragma unroll
    for (int rt = 0; rt < 4; rt++)
      acc[c][rt] = (f32x4){0.f,0.f,0.f,0.f};
  const int rtg0 = Rw >> 4;
  #pragma unroll
  for (int s = 0; s < 2; s++){
    float4 A0 = *(const float4*)(aff + s*32 + quad*8);
    float4 A1 = *(const float4*)(aff + s*32 + quad*8 + 4);
    float4 B0 = *(const float4*)(aff + 64 + s*32 + quad*8);
    float4 B1 = *(const float4*)(aff + 64 + s*32 + quad*8 + 4);
    float aA[8] = {A0.x,A0.y,A0.z,A0.w,A1.x,A1.y,A1.z,A1.w};
    float aB[8] = {B0.x,B0.y,B0.z,B0.w,B1.x,B1.y,B1.z,B1.w};
    #pragma unroll
    for (int rt = 0; rt < 4; rt++){
      uint4 u = *(const uint4*)(Yi + (((rtg0+rt)*8 + s*4 + quad)*16 + lr)*8);
      unsigned ua[4] = {u.x,u.y,u.z,u.w};
      bf16x8 xb;
      #pragma unroll
      for (int j = 0; j < 8; j++){
        unsigned wd = ua[j>>1];
        float yf = __uint_as_float((j&1) ? (wd & 0xFFFF0000u) : (wd << 16));
        float x = fmaxf(0.f, fmaf(yf, aA[j], aB[j]));
        xb[j] = (short)rnb(x);
      }
      #pragma unroll
      for (int c = 0; c < 4; c++)
        acc[c][rt] = __builtin_amdgcn_mfma_f32_16x16x32_bf16(wf[c][s], xb, acc[c][rt], 0,0,0);
    }
  }
  #pragma unroll
  for (int c = 0; c < 4; c++){
    float4 bq = *(const float4*)(bias + c*16 + quad*4);
    float bqa[4] = {bq.x, bq.y, bq.z, bq.w};
    float sv[4] = {0,0,0,0}, qv[4] = {0,0,0,0};
    int kb = c*2 + (quad>>1);
    int sub = (quad&1)*4;
    #pragma unroll
    for (int rt = 0; rt < 4; rt++){
      float y[4];
      #pragma unroll
      for (int r = 0; r < 4; r++){
        y[r] = acc[c][rt][r] + bqa[r];
        sv[r] += y[r];
        qv[r] += y[r]*y[r];
      }
      uint2 p;
      p.x = (unsigned)rnb(y[0]) | ((unsigned)rnb(y[1])<<16);
      p.y = (unsigned)rnb(y[2]) | ((unsigned)rnb(y[3])<<16);
      *(uint2*)(Yo + ((((rtg0+rt)*8 + kb)*16 + lr)*8 + sub)) = p;
    }
    float S = hred4_sum(sv, l);
    float Q = hred4_sum(qv, l);
    if ((l & 3) == 0){
      int ch = c*16 + quad*4 + ((l>>3)&1)*2 + ((l>>2)&1);
      sred[w][ch] = S;
      sred[w][64 + ch] = Q;
    }
  }
  __syncthreads();
  if (t < 128){
    float tot = sred[0][t]+sred[1][t]+sred[2][t]+sred[3][t];
    unsafeAtomicAdd(&stats[(blockIdx.x & 7)*512 + 128 + t], tot);
  }
}

// ---- conv3: Y2 -> affine+relu -> MFMA (no split) -> K-maxpool + stats. 32 rows/wave ----
__global__ __launch_bounds__(256, 2) void conv3_mfma(const unsigned short* __restrict__ Yi,
    const unsigned short* __restrict__ wpk, const float* __restrict__ bias,
    const float* __restrict__ aff, float* __restrict__ ymax,
    float* __restrict__ stats){
  __shared__ float sred[4][256];
  const int t = threadIdx.x, w = t>>6, l = t&63, quad = l>>4, lr = l&15;
  const int m0 = blockIdx.x*128;
  const int Rw = m0 + w*32;
  bf16x8 wf[8][2];
  #pragma unroll
  for (int c = 0; c < 8; c++)
    #pragma unroll
    for (int s = 0; s < 2; s++)
      wf[c][s] = *(const bf16x8*)(wpk + (((c*2+s)<<6) + l)*8);
  f32x4 acc[8][2];
  #pragma unroll
  for (int c = 0; c < 8; c++){
    acc[c][0] = (f32x4){0.f,0.f,0.f,0.f};
    acc[c][1] = (f32x4){0.f,0.f,0.f,0.f};
  }
  const int rtg0 = Rw >> 4;
  #pragma unroll
  for (int s = 0; s < 2; s++){
    float4 A0 = *(const float4*)(aff + s*32 + quad*8);
    float4 A1 = *(const float4*)(aff + s*32 + quad*8 + 4);
    float4 B0 = *(const float4*)(aff + 64 + s*32 + quad*8);
    float4 B1 = *(const float4*)(aff + 64 + s*32 + quad*8 + 4);
    float aA[8] = {A0.x,A0.y,A0.z,A0.w,A1.x,A1.y,A1.z,A1.w};
    float aB[8] = {B0.x,B0.y,B0.z,B0.w,B1.x,B1.y,B1.z,B1.w};
    #pragma unroll
    for (int rt = 0; rt < 2; rt++){
      uint4 u = *(const uint4*)(Yi + (((rtg0+rt)*8 + s*4 + quad)*16 + lr)*8);
      unsigned ua[4] = {u.x,u.y,u.z,u.w};
      bf16x8 xb;
      #pragma unroll
      for (int j = 0; j < 8; j++){
        unsigned wd = ua[j>>1];
        float yf = __uint_as_float((j&1) ? (wd & 0xFFFF0000u) : (wd << 16));
        float x = fmaxf(0.f, fmaf(yf, aA[j], aB[j]));
        xb[j] = (short)rnb(x);
      }
      #pragma unroll
      for (int c = 0; c < 8; c++)
        acc[c][rt] = __builtin_amdgcn_mfma_f32_16x16x32_bf16(wf[c][s], xb, acc[c][rt], 0,0,0);
    }
  }
  const int g = Rw >> 5;
  #pragma unroll
  for (int c = 0; c < 8; c++){
    float4 bq = *(const float4*)(bias + c*16 + quad*4);
    float bqa[4] = {bq.x, bq.y, bq.z, bq.w};
    float sv[4], qv[4], mv[4];
    #pragma unroll
    for (int r = 0; r < 4; r++){
      float y0 = acc[c][0][r] + bqa[r];
      float y1 = acc[c][1][r] + bqa[r];
      sv[r] = y0 + y1;
      qv[r] = y0*y0 + y1*y1;
      mv[r] = fmaxf(y0, y1);
    }
    float S = hred4_sum(sv, l);
    float Q = hred4_sum(qv, l);
    float Mx = hred4_max(mv, l);
    if ((l & 3) == 0){
      int ch = c*16 + quad*4 + ((l>>3)&1)*2 + ((l>>2)&1);
      sred[w][ch] = S;
      sred[w][128 + ch] = Q;
      ymax[(size_t)g*128 + ch] = Mx;
    }
  }
  __syncthreads();
  {
    float tot = sred[0][t]+sred[1][t]+sred[2][t]+sred[3][t];
    unsafeAtomicAdd(&stats[(blockIdx.x & 7)*512 + 256 + t], tot);
  }
}

__global__ void bnparam_kernel(const float* __restrict__ stats, const float* __restrict__ g,
                               const float* __restrict__ bt, float* __restrict__ outAS,
                               int sOff, int qOff, int C){
  int c = threadIdx.x;
  if (c >= C) return;
  const float inv = 1.f/(float)M_;
  float S = 0.f, Q = 0.f;
  #pragma unroll
  for (int r = 0; r < 8; r++){
    S += stats[r*512 + sOff + c];
    Q += stats[r*512 + qOff + c];
  }
  float mean = S * inv;
  float var  = Q * inv - mean*mean;
  float a = g[c] * rsqrtf(var + EPS_);
  outAS[c] = a;
  outAS[C + c] = bt[c] - mean*a;
}

__global__ void final_kernel(const float* __restrict__ ymax,
                             const float* __restrict__ affb, float* __restrict__ out){
  int t = blockIdx.x*256 + threadIdx.x;
  int o = t & 127;
  float a = affb[256 + o], s = affb[384 + o];
  out[OUT_FEAT + t] = fmaxf(0.f, a*ymax[t] + s);
}

extern "C" void kernel_launch(void* const* d_in, const int* in_sizes, int n_in,
                              void* d_out, int out_size, void* d_ws, size_t ws_size,
                              hipStream_t stream) {
  const float* xyz = (const float*)d_in[0];
  const float* nrm = (const float*)d_in[1];
  const float* pts = (const float*)d_in[2];
  const int*   fps = (const int*)d_in[3];
  const float* w0  = (const float*)d_in[4];
  const float* b0  = (const float*)d_in[5];
  const float* g0  = (const float*)d_in[6];
  const float* bt0 = (const float*)d_in[7];
  const float* w1  = (const float*)d_in[8];
  const float* b1  = (const float*)d_in[9];
  const float* g1  = (const float*)d_in[10];
  const float* bt1 = (const float*)d_in[11];
  const float* w2  = (const float*)d_in[12];
  const float* b2  = (const float*)d_in[13];
  const float* g2  = (const float*)d_in[14];
  const float* bt2 = (const float*)d_in[15];
  float* out = (float*)d_out;

  char* ws = (char*)d_ws;
  float* stats = (float*)ws;                                  // 16 KB
  float* affb  = (float*)(ws + 16384);                        // 2 KB
  int*   idxb  = (int*)(ws + 20480);                          // 2 MB
  float* ymax  = (float*)(ws + 2117632);                      // 8 MB
  unsigned short* wpack = (unsigned short*)(ws + 11554816);   // 32 KB
  unsigned short* Y1 = (unsigned short*)(ws + 18878464);      // 64 MB
  unsigned short* Y2 = (unsigned short*)(ws + 85987328);      // 64 MB

  zero_stats_kernel<<<16, 256, 0, stream>>>(stats);
  meta_kernel<<<64, 256, 0, stream>>>(xyz, nrm, fps, out);
  packw_kernel<<<64, 256, 0, stream>>>(w0, w1, w2, wpack);
  knn_kernel<<<2048, 256, 0, stream>>>(xyz, fps, idxb);
  conv1_mfma<<<2048, 256, 0, stream>>>(pts, idxb, wpack, b0, Y1, stats);
  bnparam_kernel<<<1, 64, 0, stream>>>(stats, g0, bt0, affb, 0, 64, 64);
  conv2_mfma<<<2048, 256, 0, stream>>>(Y1, wpack + 4096, b1, affb, Y2, stats);
  bnparam_kernel<<<1, 64, 0, stream>>>(stats, g1, bt1, affb + 128, 128, 192, 64);
  conv3_mfma<<<4096, 256, 0, stream>>>(Y2, wpack + 8192, b2, affb + 128, ymax, stats);
  bnparam_kernel<<<1, 128, 0, stream>>>(stats, g2, bt2, affb + 256, 256, 384, 128);
  final_kernel<<<8192, 256, 0, stream>>>(ymax, affb, out);
}